// Round 1
// baseline (355.173 us; speedup 1.0000x reference)
//
#include <hip/hip_runtime.h>
#include <math.h>

#define N_NODES 50000
#define N_EDGES 800000
#define HID     128
#define IN_DIMV 6
#define N_ACT   64
#define N_GRAPH 512

// ws layout (floats):
//   deg  [N_NODES]
//   dinv [N_NODES]
//   xs   [N_NODES*6]
//   s    [N_NODES*6]
//   gsum [N_GRAPH*HID]
//   cnt  [N_GRAPH]

__global__ void k_init(float* __restrict__ deg, float* __restrict__ gsum,
                       float* __restrict__ cnt) {
    int i = blockIdx.x * blockDim.x + threadIdx.x;
    if (i < N_NODES) deg[i] = 1.0f;               // self-loop
    if (i < N_GRAPH * HID) gsum[i] = 0.0f;
    if (i < N_GRAPH) cnt[i] = 0.0f;
}

__global__ void k_deg(const int* __restrict__ ei, float* __restrict__ deg) {
    int e = blockIdx.x * blockDim.x + threadIdx.x;
    if (e < N_EDGES) atomicAdd(&deg[ei[N_EDGES + e]], 1.0f);
}

__global__ void k_scale(const float* __restrict__ x, const int* __restrict__ batch,
                        const float* __restrict__ deg, float* __restrict__ dinv,
                        float* __restrict__ xs, float* __restrict__ s,
                        float* __restrict__ cnt) {
    int n = blockIdx.x * blockDim.x + threadIdx.x;
    if (n >= N_NODES) return;
    float dv = rsqrtf(deg[n]);   // deg >= 1 guaranteed (self-loop)
    dinv[n] = dv;
#pragma unroll
    for (int k = 0; k < IN_DIMV; ++k) {
        float v = x[n * IN_DIMV + k] * dv;
        xs[n * IN_DIMV + k] = v;
        s[n * IN_DIMV + k]  = v;   // self-loop contribution
    }
    atomicAdd(&cnt[batch[n]], 1.0f);
}

__global__ void k_scatter(const int* __restrict__ ei, const float* __restrict__ xs,
                          float* __restrict__ s) {
    int e = blockIdx.x * blockDim.x + threadIdx.x;
    if (e >= N_EDGES) return;
    int src = ei[e];
    int dst = ei[N_EDGES + e];
#pragma unroll
    for (int k = 0; k < IN_DIMV; ++k)
        atomicAdd(&s[dst * IN_DIMV + k], xs[src * IN_DIMV + k]);
}

// One block handles 16 consecutive nodes: tid = sub*128 + f.
// Each (sub,f) thread walks 8 consecutive nodes, accumulating the per-graph
// feature sum in a register and flushing (atomicAdd) on batch-id change.
__global__ __launch_bounds__(256) void k_node(const float* __restrict__ s,
                                              const float* __restrict__ dinv,
                                              const int* __restrict__ batch,
                                              const float* __restrict__ w1,
                                              const float* __restrict__ b1,
                                              float* __restrict__ gsum) {
    int f   = threadIdx.x & (HID - 1);
    int sub = threadIdx.x >> 7;
    int base = blockIdx.x * 16 + sub * 8;
    float w1r[IN_DIMV];
#pragma unroll
    for (int k = 0; k < IN_DIMV; ++k) w1r[k] = w1[k * HID + f];
    float b1f = b1[f];

    float acc = 0.0f;
    int curb = -1;
    for (int i = 0; i < 8; ++i) {
        int n = base + i;
        if (n >= N_NODES) break;
        float t = 0.0f;
#pragma unroll
        for (int k = 0; k < IN_DIMV; ++k) t = fmaf(s[n * IN_DIMV + k], w1r[k], t);
        float a = fmaxf(fmaf(dinv[n], t, b1f), 0.0f);
        int b = batch[n];
        if (b != curb) {
            if (curb >= 0) atomicAdd(&gsum[curb * HID + f], acc);
            acc = 0.0f;
            curb = b;
        }
        acc += a;
    }
    if (curb >= 0) atomicAdd(&gsum[curb * HID + f], acc);
}

// One block per graph: mean -> 128x128 MLP + ReLU -> 128x64 head -> log_softmax.
__global__ __launch_bounds__(128) void k_head(const float* __restrict__ gsum,
                                              const float* __restrict__ cnt,
                                              const float* __restrict__ wl,
                                              const float* __restrict__ bl,
                                              const float* __restrict__ w2,
                                              const float* __restrict__ b2,
                                              float* __restrict__ out) {
    __shared__ float sg[HID];
    __shared__ float sg2[HID];
    int g = blockIdx.x;
    int t = threadIdx.x;

    float ic = 1.0f / fmaxf(cnt[g], 1.0f);
    sg[t] = gsum[g * HID + t] * ic;
    __syncthreads();

    float acc = bl[t];
    for (int k = 0; k < HID; ++k) acc = fmaf(sg[k], wl[k * HID + t], acc);
    sg2[t] = fmaxf(acc, 0.0f);
    __syncthreads();

    if (t < N_ACT) {
        float l = b2[t];
        for (int f = 0; f < HID; ++f) l = fmaf(sg2[f], w2[f * N_ACT + t], l);
        // wave-level reduce over the 64 lanes of wave 0
        float m = l;
#pragma unroll
        for (int off = 32; off > 0; off >>= 1) m = fmaxf(m, __shfl_xor(m, off));
        float e = expf(l - m);
        float ssum = e;
#pragma unroll
        for (int off = 32; off > 0; off >>= 1) ssum += __shfl_xor(ssum, off);
        out[g * N_ACT + t] = l - m - logf(ssum);
    }
}

extern "C" void kernel_launch(void* const* d_in, const int* in_sizes, int n_in,
                              void* d_out, int out_size, void* d_ws, size_t ws_size,
                              hipStream_t stream) {
    const float* x     = (const float*)d_in[0];
    const int*   ei    = (const int*)d_in[1];
    const int*   batch = (const int*)d_in[2];
    const float* w1    = (const float*)d_in[3];
    const float* b1    = (const float*)d_in[4];
    const float* wl    = (const float*)d_in[5];
    const float* bl    = (const float*)d_in[6];
    const float* w2    = (const float*)d_in[7];
    const float* b2    = (const float*)d_in[8];
    float* out = (float*)d_out;

    float* ws   = (float*)d_ws;
    float* deg  = ws;
    float* dinv = deg + N_NODES;
    float* xs   = dinv + N_NODES;
    float* s    = xs + N_NODES * IN_DIMV;
    float* gsum = s + N_NODES * IN_DIMV;
    float* cnt  = gsum + N_GRAPH * HID;

    k_init<<<(N_GRAPH * HID + 255) / 256, 256, 0, stream>>>(deg, gsum, cnt);
    k_deg<<<(N_EDGES + 255) / 256, 256, 0, stream>>>(ei, deg);
    k_scale<<<(N_NODES + 255) / 256, 256, 0, stream>>>(x, batch, deg, dinv, xs, s, cnt);
    k_scatter<<<(N_EDGES + 255) / 256, 256, 0, stream>>>(ei, xs, s);
    k_node<<<(N_NODES + 15) / 16, 256, 0, stream>>>(s, dinv, batch, w1, b1, gsum);
    k_head<<<N_GRAPH, 128, 0, stream>>>(gsum, cnt, wl, bl, w2, b2, out);
}

// Round 2
// 250.704 us; speedup vs baseline: 1.4167x; 1.4167x over previous
//
#include <hip/hip_runtime.h>
#include <math.h>

#define N_NODES 50000
#define N_EDGES 800000
#define HID     128
#define IN_DIMV 6
#define N_ACT   64
#define N_GRAPH 512
#define N6      (N_NODES * 6)

// ---- fast-path tiling ----
#define CD   32                         // deg edge-chunks
#define NWD  8192                       // deg window nodes (32KB LDS)
#define WD   7                          // ceil(50000/8192)
#define CF   16                         // feature edge-chunks
#define NWF  2048                       // feature window nodes (48KB LDS)
#define WF   25                         // ceil(50000/2048)
#define ECD  ((N_EDGES + CD - 1) / CD)
#define ECF  ((N_EDGES + CF - 1) / CF)

// fast ws layout (floats):
//   deg_part [CD][N_NODES]
//   s_part   [CF][N6]
//   xs_pad   [N_NODES*8]   (6 scaled feats + 2 pad, float4-aligned)
//   dinv     [N_NODES]
//   gsum     [N_GRAPH*HID]
//   cnt      [N_GRAPH]
#define F_DEGPART 0
#define F_SPART   (F_DEGPART + CD * N_NODES)
#define F_XSPAD   (F_SPART + CF * N6)
#define F_DINV    (F_XSPAD + N_NODES * 8)
#define F_GSUM    (F_DINV + N_NODES)
#define F_CNT     (F_GSUM + N_GRAPH * HID)
#define F_TOTAL   (F_CNT + N_GRAPH)
#define NEED_BYTES ((size_t)F_TOTAL * 4)

// ===================== fast path =====================

__global__ void k_init_f(float* __restrict__ gsum, float* __restrict__ cnt) {
    int i = blockIdx.x * blockDim.x + threadIdx.x;
    if (i < N_GRAPH * HID) gsum[i] = 0.0f;
    if (i < N_GRAPH) cnt[i] = 0.0f;
}

__global__ __launch_bounds__(256) void k_deg_w(const int* __restrict__ ei,
                                               float* __restrict__ deg_part) {
    __shared__ float h[NWD];
    int w = blockIdx.x, c = blockIdx.y;
    int base = w * NWD;
    for (int i = threadIdx.x; i < NWD; i += 256) h[i] = 0.0f;
    __syncthreads();
    int e1 = min((c + 1) * ECD, N_EDGES);
    for (int e = c * ECD + threadIdx.x; e < e1; e += 256) {
        unsigned u = (unsigned)(ei[N_EDGES + e] - base);
        if (u < NWD) atomicAdd(&h[u], 1.0f);
    }
    __syncthreads();
    for (int i = threadIdx.x; i < NWD; i += 256) {
        int n = base + i;
        if (n < N_NODES) deg_part[c * N_NODES + n] = h[i];
    }
}

__global__ __launch_bounds__(256) void k_scale_f(const float* __restrict__ x,
                                                 const int* __restrict__ batch,
                                                 const float* __restrict__ deg_part,
                                                 float* __restrict__ dinv,
                                                 float* __restrict__ xs_pad,
                                                 float* __restrict__ cnt) {
    int n = blockIdx.x * 256 + threadIdx.x;
    if (n >= N_NODES) return;
    float d = 1.0f;                      // self-loop
#pragma unroll 8
    for (int c = 0; c < CD; ++c) d += deg_part[c * N_NODES + n];
    float dv = rsqrtf(d);
    dinv[n] = dv;
    float4 a, b;
    a.x = x[n * 6 + 0] * dv; a.y = x[n * 6 + 1] * dv;
    a.z = x[n * 6 + 2] * dv; a.w = x[n * 6 + 3] * dv;
    b.x = x[n * 6 + 4] * dv; b.y = x[n * 6 + 5] * dv;
    b.z = 0.0f; b.w = 0.0f;
    ((float4*)(xs_pad + n * 8))[0] = a;
    ((float4*)(xs_pad + n * 8))[1] = b;
    atomicAdd(&cnt[batch[n]], 1.0f);
}

__global__ __launch_bounds__(256) void k_feat_w(const int* __restrict__ ei,
                                                const float* __restrict__ xs_pad,
                                                float* __restrict__ s_part) {
    __shared__ float h[NWF * 6];
    int w = blockIdx.x, c = blockIdx.y;
    int base = w * NWF;
    for (int i = threadIdx.x; i < NWF * 6; i += 256) h[i] = 0.0f;
    __syncthreads();
    int e1 = min((c + 1) * ECF, N_EDGES);
    for (int e = c * ECF + threadIdx.x; e < e1; e += 256) {
        unsigned u = (unsigned)(ei[N_EDGES + e] - base);
        if (u < NWF) {
            int src = ei[e];
            const float4* xp = (const float4*)(xs_pad + src * 8);
            float4 a = xp[0], b = xp[1];
            float* hp = &h[u * 6];
            atomicAdd(hp + 0, a.x); atomicAdd(hp + 1, a.y); atomicAdd(hp + 2, a.z);
            atomicAdd(hp + 3, a.w); atomicAdd(hp + 4, b.x); atomicAdd(hp + 5, b.y);
        }
    }
    __syncthreads();
    int gb = base * 6;
    for (int i = threadIdx.x; i < NWF * 6; i += 256) {
        int g = gb + i;
        if (g < N6) s_part[c * N6 + g] = h[i];
    }
}

// block: 64 nodes; cooperative partial-reduce into LDS, then W1+ReLU and
// run-accumulated per-graph flush (batch sorted -> ~1 atomic per thread).
__global__ __launch_bounds__(256) void k_node_f(const float* __restrict__ s_part,
                                                const float* __restrict__ xs_pad,
                                                const float* __restrict__ dinv,
                                                const int* __restrict__ batch,
                                                const float* __restrict__ w1,
                                                const float* __restrict__ b1,
                                                float* __restrict__ gsum) {
    __shared__ float sb[64 * 6];
    __shared__ float dvb[64];
    __shared__ int   btb[64];
    int nb0 = blockIdx.x * 64;
    for (int i = threadIdx.x; i < 64 * 6; i += 256) {
        int g = nb0 * 6 + i;
        float v = 0.0f;
        if (g < N6) {
            v = xs_pad[(g / 6) * 8 + (g % 6)];   // self-loop term
#pragma unroll 8
            for (int c = 0; c < CF; ++c) v += s_part[c * N6 + g];
        }
        sb[i] = v;
    }
    if (threadIdx.x < 64) {
        int n = nb0 + threadIdx.x;
        dvb[threadIdx.x] = (n < N_NODES) ? dinv[n] : 0.0f;
        btb[threadIdx.x] = (n < N_NODES) ? batch[n] : -1;
    }
    __syncthreads();
    int f = threadIdx.x & (HID - 1);
    int sub = threadIdx.x >> 7;
    float w1r[6];
#pragma unroll
    for (int k = 0; k < 6; ++k) w1r[k] = w1[k * HID + f];
    float b1f = b1[f];
    float acc = 0.0f;
    int curb = -1;
    int l0 = sub * 32;
    for (int i = 0; i < 32; ++i) {
        int n = nb0 + l0 + i;
        if (n >= N_NODES) break;
        const float* sp = &sb[(l0 + i) * 6];
        float t = 0.0f;
#pragma unroll
        for (int k = 0; k < 6; ++k) t = fmaf(sp[k], w1r[k], t);
        float a = fmaxf(fmaf(dvb[l0 + i], t, b1f), 0.0f);
        int b = btb[l0 + i];
        if (b != curb) {
            if (curb >= 0) atomicAdd(&gsum[curb * HID + f], acc);
            acc = 0.0f;
            curb = b;
        }
        acc += a;
    }
    if (curb >= 0) atomicAdd(&gsum[curb * HID + f], acc);
}

__global__ __launch_bounds__(128) void k_head(const float* __restrict__ gsum,
                                              const float* __restrict__ cnt,
                                              const float* __restrict__ wl,
                                              const float* __restrict__ bl,
                                              const float* __restrict__ w2,
                                              const float* __restrict__ b2,
                                              float* __restrict__ out) {
    __shared__ float sg[HID];
    __shared__ float sg2[HID];
    int g = blockIdx.x;
    int t = threadIdx.x;

    float ic = 1.0f / fmaxf(cnt[g], 1.0f);
    sg[t] = gsum[g * HID + t] * ic;
    __syncthreads();

    float acc = bl[t];
    for (int k = 0; k < HID; ++k) acc = fmaf(sg[k], wl[k * HID + t], acc);
    sg2[t] = fmaxf(acc, 0.0f);
    __syncthreads();

    if (t < N_ACT) {
        float l = b2[t];
        for (int f = 0; f < HID; ++f) l = fmaf(sg2[f], w2[f * N_ACT + t], l);
        float m = l;
#pragma unroll
        for (int off = 32; off > 0; off >>= 1) m = fmaxf(m, __shfl_xor(m, off));
        float e = expf(l - m);
        float ssum = e;
#pragma unroll
        for (int off = 32; off > 0; off >>= 1) ssum += __shfl_xor(ssum, off);
        out[g * N_ACT + t] = l - m - logf(ssum);
    }
}

// ===================== fallback path (round-1, known-correct) =====================

__global__ void k_init(float* __restrict__ deg, float* __restrict__ gsum,
                       float* __restrict__ cnt) {
    int i = blockIdx.x * blockDim.x + threadIdx.x;
    if (i < N_NODES) deg[i] = 1.0f;
    if (i < N_GRAPH * HID) gsum[i] = 0.0f;
    if (i < N_GRAPH) cnt[i] = 0.0f;
}

__global__ void k_deg(const int* __restrict__ ei, float* __restrict__ deg) {
    int e = blockIdx.x * blockDim.x + threadIdx.x;
    if (e < N_EDGES) atomicAdd(&deg[ei[N_EDGES + e]], 1.0f);
}

__global__ void k_scale(const float* __restrict__ x, const int* __restrict__ batch,
                        const float* __restrict__ deg, float* __restrict__ dinv,
                        float* __restrict__ xs, float* __restrict__ s,
                        float* __restrict__ cnt) {
    int n = blockIdx.x * blockDim.x + threadIdx.x;
    if (n >= N_NODES) return;
    float dv = rsqrtf(deg[n]);
    dinv[n] = dv;
#pragma unroll
    for (int k = 0; k < IN_DIMV; ++k) {
        float v = x[n * IN_DIMV + k] * dv;
        xs[n * IN_DIMV + k] = v;
        s[n * IN_DIMV + k] = v;
    }
    atomicAdd(&cnt[batch[n]], 1.0f);
}

__global__ void k_scatter(const int* __restrict__ ei, const float* __restrict__ xs,
                          float* __restrict__ s) {
    int e = blockIdx.x * blockDim.x + threadIdx.x;
    if (e >= N_EDGES) return;
    int src = ei[e];
    int dst = ei[N_EDGES + e];
#pragma unroll
    for (int k = 0; k < IN_DIMV; ++k)
        atomicAdd(&s[dst * IN_DIMV + k], xs[src * IN_DIMV + k]);
}

__global__ __launch_bounds__(256) void k_node(const float* __restrict__ s,
                                              const float* __restrict__ dinv,
                                              const int* __restrict__ batch,
                                              const float* __restrict__ w1,
                                              const float* __restrict__ b1,
                                              float* __restrict__ gsum) {
    int f = threadIdx.x & (HID - 1);
    int sub = threadIdx.x >> 7;
    int base = blockIdx.x * 16 + sub * 8;
    float w1r[IN_DIMV];
#pragma unroll
    for (int k = 0; k < IN_DIMV; ++k) w1r[k] = w1[k * HID + f];
    float b1f = b1[f];
    float acc = 0.0f;
    int curb = -1;
    for (int i = 0; i < 8; ++i) {
        int n = base + i;
        if (n >= N_NODES) break;
        float t = 0.0f;
#pragma unroll
        for (int k = 0; k < IN_DIMV; ++k) t = fmaf(s[n * IN_DIMV + k], w1r[k], t);
        float a = fmaxf(fmaf(dinv[n], t, b1f), 0.0f);
        int b = batch[n];
        if (b != curb) {
            if (curb >= 0) atomicAdd(&gsum[curb * HID + f], acc);
            acc = 0.0f;
            curb = b;
        }
        acc += a;
    }
    if (curb >= 0) atomicAdd(&gsum[curb * HID + f], acc);
}

// ===================== launch =====================

extern "C" void kernel_launch(void* const* d_in, const int* in_sizes, int n_in,
                              void* d_out, int out_size, void* d_ws, size_t ws_size,
                              hipStream_t stream) {
    const float* x     = (const float*)d_in[0];
    const int*   ei    = (const int*)d_in[1];
    const int*   batch = (const int*)d_in[2];
    const float* w1    = (const float*)d_in[3];
    const float* b1    = (const float*)d_in[4];
    const float* wl    = (const float*)d_in[5];
    const float* bl    = (const float*)d_in[6];
    const float* w2    = (const float*)d_in[7];
    const float* b2    = (const float*)d_in[8];
    float* out = (float*)d_out;
    float* ws = (float*)d_ws;

    if (ws_size >= NEED_BYTES) {
        float* deg_part = ws + F_DEGPART;
        float* s_part   = ws + F_SPART;
        float* xs_pad   = ws + F_XSPAD;
        float* dinv     = ws + F_DINV;
        float* gsum     = ws + F_GSUM;
        float* cnt      = ws + F_CNT;

        k_init_f<<<(N_GRAPH * HID + 255) / 256, 256, 0, stream>>>(gsum, cnt);
        k_deg_w<<<dim3(WD, CD), 256, 0, stream>>>(ei, deg_part);
        k_scale_f<<<(N_NODES + 255) / 256, 256, 0, stream>>>(x, batch, deg_part, dinv, xs_pad, cnt);
        k_feat_w<<<dim3(WF, CF), 256, 0, stream>>>(ei, xs_pad, s_part);
        k_node_f<<<(N_NODES + 63) / 64, 256, 0, stream>>>(s_part, xs_pad, dinv, batch, w1, b1, gsum);
        k_head<<<N_GRAPH, 128, 0, stream>>>(gsum, cnt, wl, bl, w2, b2, out);
    } else {
        float* deg  = ws;
        float* dinv = deg + N_NODES;
        float* xs   = dinv + N_NODES;
        float* s    = xs + N6;
        float* gsum = s + N6;
        float* cnt  = gsum + N_GRAPH * HID;

        k_init<<<(N_GRAPH * HID + 255) / 256, 256, 0, stream>>>(deg, gsum, cnt);
        k_deg<<<(N_EDGES + 255) / 256, 256, 0, stream>>>(ei, deg);
        k_scale<<<(N_NODES + 255) / 256, 256, 0, stream>>>(x, batch, deg, dinv, xs, s, cnt);
        k_scatter<<<(N_EDGES + 255) / 256, 256, 0, stream>>>(ei, xs, s);
        k_node<<<(N_NODES + 15) / 16, 256, 0, stream>>>(s, dinv, batch, w1, b1, gsum);
        k_head<<<N_GRAPH, 128, 0, stream>>>(gsum, cnt, wl, bl, w2, b2, out);
    }
}

// Round 3
// 126.247 us; speedup vs baseline: 2.8133x; 1.9858x over previous
//
#include <hip/hip_runtime.h>
#include <math.h>

#define N_NODES 50000
#define N_EDGES 800000
#define HID     128
#define N_ACT   64
#define N_GRAPH 512
#define N6      (N_NODES * 6)

// bucketing config
#define NWF   2048                 // nodes per dst-window
#define LOGW  11
#define WF    25                   // ceil(50000/2048)
#define CAP   40960                // bucket capacity (mean 32768, sigma ~177)
#define CB    16                   // sub-chunks per window in feat pass
#define DC    4                    // sub-chunks per window in deg pass
#define EPB   2048                 // edges per place-block
#define PB    ((N_EDGES + EPB - 1) / EPB)

// ws layout (float-sized slots)
#define F_BUCKET 0                          // WF*CAP ints
#define F_CURSOR (F_BUCKET + WF * CAP)      // 32 ints
#define F_DEGP   (F_CURSOR + 32)            // DC*N_NODES floats
#define F_DINV   (F_DEGP + DC * N_NODES)    // N_NODES
#define F_XSPAD  (F_DINV + N_NODES)         // N_NODES*8
#define F_SPART  (F_XSPAD + N_NODES * 8)    // CB*N6
#define F_GSUM   (F_SPART + CB * N6)        // N_GRAPH*HID
#define F_CNT    (F_GSUM + N_GRAPH * HID)   // N_GRAPH
#define F_TOTAL  (F_CNT + N_GRAPH)
#define NEED_BYTES ((size_t)F_TOTAL * 4)

// ===================== fast path =====================

__global__ void k_init_f(float* __restrict__ gsum, float* __restrict__ cnt,
                         int* __restrict__ cursor) {
    int i = blockIdx.x * blockDim.x + threadIdx.x;
    if (i < N_GRAPH * HID) gsum[i] = 0.0f;
    if (i < N_GRAPH) cnt[i] = 0.0f;
    if (i < 32) cursor[i] = 0;
}

__global__ __launch_bounds__(256) void k_place(const int* __restrict__ ei,
                                               int* __restrict__ bucket,
                                               int* __restrict__ cursor) {
    __shared__ int lc[WF], lb[WF];
    if (threadIdx.x < WF) lc[threadIdx.x] = 0;
    __syncthreads();
    int e0 = blockIdx.x * EPB;
    int pk[8], wl[8];
#pragma unroll
    for (int i = 0; i < 8; ++i) {
        int e = e0 + i * 256 + threadIdx.x;
        wl[i] = -1;
        if (e < N_EDGES) {
            int src = ei[e], dst = ei[N_EDGES + e];
            int w = dst >> LOGW;
            int lp = atomicAdd(&lc[w], 1);          // local slot within (block, window)
            pk[i] = ((dst - (w << LOGW)) << 16) | src;
            wl[i] = (w << 16) | lp;
        }
    }
    __syncthreads();
    if (threadIdx.x < WF)
        lb[threadIdx.x] = atomicAdd(&cursor[threadIdx.x], lc[threadIdx.x]);
    __syncthreads();
#pragma unroll
    for (int i = 0; i < 8; ++i) {
        if (wl[i] >= 0) {
            int w = wl[i] >> 16, lp = wl[i] & 0xffff;
            int pos = lb[w] + lp;
            if (pos < CAP) bucket[w * CAP + pos] = pk[i];
        }
    }
}

__global__ __launch_bounds__(256) void k_degb(const int* __restrict__ bucket,
                                              const int* __restrict__ cursor,
                                              float* __restrict__ degp) {
    __shared__ float hc[NWF];
    int w = blockIdx.x, c = blockIdx.y;
    float4* h4 = (float4*)hc;
    for (int i = threadIdx.x; i < NWF / 4; i += 256) h4[i] = make_float4(0, 0, 0, 0);
    __syncthreads();
    int cw = cursor[w];
    const int* bp = bucket + w * CAP;
    for (int e = c * 256 + threadIdx.x; e < cw; e += DC * 256)
        atomicAdd(&hc[((unsigned)bp[e]) >> 16], 1.0f);
    __syncthreads();
    int nb = w * NWF;
    for (int i = threadIdx.x; i < NWF; i += 256) {
        int n = nb + i;
        if (n < N_NODES) degp[c * N_NODES + n] = hc[i];
    }
}

__global__ __launch_bounds__(256) void k_scale_f(const float* __restrict__ x,
                                                 const int* __restrict__ batch,
                                                 const float* __restrict__ degp,
                                                 float* __restrict__ dinv,
                                                 float* __restrict__ xs_pad,
                                                 float* __restrict__ cnt) {
    int n = blockIdx.x * 256 + threadIdx.x;
    if (n >= N_NODES) return;
    float d = 1.0f;                       // self-loop
#pragma unroll
    for (int c = 0; c < DC; ++c) d += degp[c * N_NODES + n];
    float dv = rsqrtf(d);
    dinv[n] = dv;
    float4 a, b;
    a.x = x[n * 6 + 0] * dv; a.y = x[n * 6 + 1] * dv;
    a.z = x[n * 6 + 2] * dv; a.w = x[n * 6 + 3] * dv;
    b.x = x[n * 6 + 4] * dv; b.y = x[n * 6 + 5] * dv;
    b.z = 0.0f; b.w = 0.0f;
    ((float4*)(xs_pad + n * 8))[0] = a;
    ((float4*)(xs_pad + n * 8))[1] = b;
    atomicAdd(&cnt[batch[n]], 1.0f);
}

__global__ __launch_bounds__(256) void k_feat_b(const int* __restrict__ bucket,
                                                const int* __restrict__ cursor,
                                                const float* __restrict__ xs_pad,
                                                float* __restrict__ s_part) {
    __shared__ float h[NWF * 6];
    int w = blockIdx.x, c = blockIdx.y;
    float4* h4 = (float4*)h;
    for (int i = threadIdx.x; i < NWF * 6 / 4; i += 256) h4[i] = make_float4(0, 0, 0, 0);
    __syncthreads();
    int cw = cursor[w];
    const int* bp = bucket + w * CAP;
    for (int e = c * 256 + threadIdx.x; e < cw; e += CB * 256) {
        int p = bp[e];
        int u = ((unsigned)p) >> 16;
        int src = p & 0xffff;
        const float4* xp = (const float4*)(xs_pad + src * 8);
        float4 a = xp[0], b = xp[1];
        float* hp = &h[u * 6];
        atomicAdd(hp + 0, a.x); atomicAdd(hp + 1, a.y); atomicAdd(hp + 2, a.z);
        atomicAdd(hp + 3, a.w); atomicAdd(hp + 4, b.x); atomicAdd(hp + 5, b.y);
    }
    __syncthreads();
    int gb = w * NWF * 6;
    int lim = min(NWF * 6, N6 - gb);      // multiple of 4
    float4* sp4 = (float4*)(s_part + c * N6 + gb);
    for (int i = threadIdx.x; i < lim / 4; i += 256) sp4[i] = h4[i];
}

// block: 64 nodes; partial-reduce into LDS, then W1+ReLU and run-accumulated
// per-graph flush (batch sorted -> ~1 atomic per thread).
__global__ __launch_bounds__(256) void k_node_f(const float* __restrict__ s_part,
                                                const float* __restrict__ xs_pad,
                                                const float* __restrict__ dinv,
                                                const int* __restrict__ batch,
                                                const float* __restrict__ w1,
                                                const float* __restrict__ b1,
                                                float* __restrict__ gsum) {
    __shared__ float sb[64 * 6];
    __shared__ float dvb[64];
    __shared__ int   btb[64];
    int nb0 = blockIdx.x * 64;
    for (int i = threadIdx.x; i < 64 * 6; i += 256) {
        int g = nb0 * 6 + i;
        float v = 0.0f;
        if (g < N6) {
            v = xs_pad[(g / 6) * 8 + (g % 6)];   // self-loop term
#pragma unroll 8
            for (int c = 0; c < CB; ++c) v += s_part[c * N6 + g];
        }
        sb[i] = v;
    }
    if (threadIdx.x < 64) {
        int n = nb0 + threadIdx.x;
        dvb[threadIdx.x] = (n < N_NODES) ? dinv[n] : 0.0f;
        btb[threadIdx.x] = (n < N_NODES) ? batch[n] : -1;
    }
    __syncthreads();
    int f = threadIdx.x & (HID - 1);
    int sub = threadIdx.x >> 7;
    float w1r[6];
#pragma unroll
    for (int k = 0; k < 6; ++k) w1r[k] = w1[k * HID + f];
    float b1f = b1[f];
    float acc = 0.0f;
    int curb = -1;
    int l0 = sub * 32;
    for (int i = 0; i < 32; ++i) {
        int n = nb0 + l0 + i;
        if (n >= N_NODES) break;
        const float* sp = &sb[(l0 + i) * 6];
        float t = 0.0f;
#pragma unroll
        for (int k = 0; k < 6; ++k) t = fmaf(sp[k], w1r[k], t);
        float a = fmaxf(fmaf(dvb[l0 + i], t, b1f), 0.0f);
        int b = btb[l0 + i];
        if (b != curb) {
            if (curb >= 0) atomicAdd(&gsum[curb * HID + f], acc);
            acc = 0.0f;
            curb = b;
        }
        acc += a;
    }
    if (curb >= 0) atomicAdd(&gsum[curb * HID + f], acc);
}

__global__ __launch_bounds__(128) void k_head(const float* __restrict__ gsum,
                                              const float* __restrict__ cnt,
                                              const float* __restrict__ wl,
                                              const float* __restrict__ bl,
                                              const float* __restrict__ w2,
                                              const float* __restrict__ b2,
                                              float* __restrict__ out) {
    __shared__ float sg[HID];
    __shared__ float sg2[HID];
    int g = blockIdx.x;
    int t = threadIdx.x;

    float ic = 1.0f / fmaxf(cnt[g], 1.0f);
    sg[t] = gsum[g * HID + t] * ic;
    __syncthreads();

    float acc = bl[t];
    for (int k = 0; k < HID; ++k) acc = fmaf(sg[k], wl[k * HID + t], acc);
    sg2[t] = fmaxf(acc, 0.0f);
    __syncthreads();

    if (t < N_ACT) {
        float l = b2[t];
        for (int f = 0; f < HID; ++f) l = fmaf(sg2[f], w2[f * N_ACT + t], l);
        float m = l;
#pragma unroll
        for (int off = 32; off > 0; off >>= 1) m = fmaxf(m, __shfl_xor(m, off));
        float e = expf(l - m);
        float ssum = e;
#pragma unroll
        for (int off = 32; off > 0; off >>= 1) ssum += __shfl_xor(ssum, off);
        out[g * N_ACT + t] = l - m - logf(ssum);
    }
}

// ===================== fallback path (round-1, known-correct) =====================

__global__ void k_init(float* __restrict__ deg, float* __restrict__ gsum,
                       float* __restrict__ cnt) {
    int i = blockIdx.x * blockDim.x + threadIdx.x;
    if (i < N_NODES) deg[i] = 1.0f;
    if (i < N_GRAPH * HID) gsum[i] = 0.0f;
    if (i < N_GRAPH) cnt[i] = 0.0f;
}

__global__ void k_deg(const int* __restrict__ ei, float* __restrict__ deg) {
    int e = blockIdx.x * blockDim.x + threadIdx.x;
    if (e < N_EDGES) atomicAdd(&deg[ei[N_EDGES + e]], 1.0f);
}

__global__ void k_scale(const float* __restrict__ x, const int* __restrict__ batch,
                        const float* __restrict__ deg, float* __restrict__ dinv,
                        float* __restrict__ xs, float* __restrict__ s,
                        float* __restrict__ cnt) {
    int n = blockIdx.x * blockDim.x + threadIdx.x;
    if (n >= N_NODES) return;
    float dv = rsqrtf(deg[n]);
    dinv[n] = dv;
#pragma unroll
    for (int k = 0; k < 6; ++k) {
        float v = x[n * 6 + k] * dv;
        xs[n * 6 + k] = v;
        s[n * 6 + k] = v;
    }
    atomicAdd(&cnt[batch[n]], 1.0f);
}

__global__ void k_scatter(const int* __restrict__ ei, const float* __restrict__ xs,
                          float* __restrict__ s) {
    int e = blockIdx.x * blockDim.x + threadIdx.x;
    if (e >= N_EDGES) return;
    int src = ei[e];
    int dst = ei[N_EDGES + e];
#pragma unroll
    for (int k = 0; k < 6; ++k)
        atomicAdd(&s[dst * 6 + k], xs[src * 6 + k]);
}

__global__ __launch_bounds__(256) void k_node(const float* __restrict__ s,
                                              const float* __restrict__ dinv,
                                              const int* __restrict__ batch,
                                              const float* __restrict__ w1,
                                              const float* __restrict__ b1,
                                              float* __restrict__ gsum) {
    int f = threadIdx.x & (HID - 1);
    int sub = threadIdx.x >> 7;
    int base = blockIdx.x * 16 + sub * 8;
    float w1r[6];
#pragma unroll
    for (int k = 0; k < 6; ++k) w1r[k] = w1[k * HID + f];
    float b1f = b1[f];
    float acc = 0.0f;
    int curb = -1;
    for (int i = 0; i < 8; ++i) {
        int n = base + i;
        if (n >= N_NODES) break;
        float t = 0.0f;
#pragma unroll
        for (int k = 0; k < 6; ++k) t = fmaf(s[n * 6 + k], w1r[k], t);
        float a = fmaxf(fmaf(dinv[n], t, b1f), 0.0f);
        int b = batch[n];
        if (b != curb) {
            if (curb >= 0) atomicAdd(&gsum[curb * HID + f], acc);
            acc = 0.0f;
            curb = b;
        }
        acc += a;
    }
    if (curb >= 0) atomicAdd(&gsum[curb * HID + f], acc);
}

// ===================== launch =====================

extern "C" void kernel_launch(void* const* d_in, const int* in_sizes, int n_in,
                              void* d_out, int out_size, void* d_ws, size_t ws_size,
                              hipStream_t stream) {
    const float* x     = (const float*)d_in[0];
    const int*   ei    = (const int*)d_in[1];
    const int*   batch = (const int*)d_in[2];
    const float* w1    = (const float*)d_in[3];
    const float* b1    = (const float*)d_in[4];
    const float* wl    = (const float*)d_in[5];
    const float* bl    = (const float*)d_in[6];
    const float* w2    = (const float*)d_in[7];
    const float* b2    = (const float*)d_in[8];
    float* out = (float*)d_out;
    float* ws = (float*)d_ws;

    if (ws_size >= NEED_BYTES) {
        int*   bucket = (int*)(ws + F_BUCKET);
        int*   cursor = (int*)(ws + F_CURSOR);
        float* degp   = ws + F_DEGP;
        float* dinv   = ws + F_DINV;
        float* xs_pad = ws + F_XSPAD;
        float* s_part = ws + F_SPART;
        float* gsum   = ws + F_GSUM;
        float* cnt    = ws + F_CNT;

        k_init_f<<<(N_GRAPH * HID + 255) / 256, 256, 0, stream>>>(gsum, cnt, cursor);
        k_place<<<PB, 256, 0, stream>>>(ei, bucket, cursor);
        k_degb<<<dim3(WF, DC), 256, 0, stream>>>(bucket, cursor, degp);
        k_scale_f<<<(N_NODES + 255) / 256, 256, 0, stream>>>(x, batch, degp, dinv, xs_pad, cnt);
        k_feat_b<<<dim3(WF, CB), 256, 0, stream>>>(bucket, cursor, xs_pad, s_part);
        k_node_f<<<(N_NODES + 63) / 64, 256, 0, stream>>>(s_part, xs_pad, dinv, batch, w1, b1, gsum);
        k_head<<<N_GRAPH, 128, 0, stream>>>(gsum, cnt, wl, bl, w2, b2, out);
    } else {
        float* deg  = ws;
        float* dinv = deg + N_NODES;
        float* xs   = dinv + N_NODES;
        float* s    = xs + N6;
        float* gsum = s + N6;
        float* cnt  = gsum + N_GRAPH * HID;

        k_init<<<(N_GRAPH * HID + 255) / 256, 256, 0, stream>>>(deg, gsum, cnt);
        k_deg<<<(N_EDGES + 255) / 256, 256, 0, stream>>>(ei, deg);
        k_scale<<<(N_NODES + 255) / 256, 256, 0, stream>>>(x, batch, deg, dinv, xs, s, cnt);
        k_scatter<<<(N_EDGES + 255) / 256, 256, 0, stream>>>(ei, xs, s);
        k_node<<<(N_NODES + 15) / 16, 256, 0, stream>>>(s, dinv, batch, w1, b1, gsum);
        k_head<<<N_GRAPH, 128, 0, stream>>>(gsum, cnt, wl, bl, w2, b2, out);
    }
}

// Round 4
// 111.261 us; speedup vs baseline: 3.1922x; 1.1347x over previous
//
#include <hip/hip_runtime.h>
#include <math.h>

#define N_NODES 50000
#define N_EDGES 800000
#define HID     128
#define N_ACT   64
#define N_GRAPH 512
#define N6      (N_NODES * 6)

// bucketing config
#define NWF   2048                 // nodes per dst-window
#define LOGW  11
#define WF    25                   // ceil(50000/2048)
#define CAP   40960                // bucket capacity (mean 32000)
#define CB    8                    // sub-chunks per window in feat pass
#define DC    4                    // sub-chunks per window in deg pass
#define EPB   2048                 // edges per place-block
#define PB    ((N_EDGES + EPB - 1) / EPB)

// node-stage config
#define NBLK    512                // nodes per k_node_f block
#define MAXSPAN 16                 // max graphs spanned by one block (LDS path)

// ws layout (float-sized slots)
#define F_BUCKET 0                          // WF*CAP ints
#define F_CURSOR (F_BUCKET + WF * CAP)      // 32 ints
#define F_DEGP   (F_CURSOR + 32)            // DC*N_NODES floats
#define F_DINV   (F_DEGP + DC * N_NODES)    // N_NODES
#define F_XSPAD  (F_DINV + N_NODES)         // N_NODES*8
#define F_SPART  (F_XSPAD + N_NODES * 8)    // CB*N6
#define F_GSUM   (F_SPART + CB * N6)        // N_GRAPH*HID
#define F_CNT    (F_GSUM + N_GRAPH * HID)   // N_GRAPH
#define F_TOTAL  (F_CNT + N_GRAPH)
#define NEED_BYTES ((size_t)F_TOTAL * 4)

// ===================== fast path =====================

__global__ void k_init_f(float* __restrict__ gsum, float* __restrict__ cnt,
                         int* __restrict__ cursor) {
    int i = blockIdx.x * blockDim.x + threadIdx.x;
    if (i < N_GRAPH * HID) gsum[i] = 0.0f;
    if (i < N_GRAPH) cnt[i] = 0.0f;
    if (i < 32) cursor[i] = 0;
}

__global__ __launch_bounds__(256) void k_place(const int* __restrict__ ei,
                                               int* __restrict__ bucket,
                                               int* __restrict__ cursor) {
    __shared__ int lc[WF], lb[WF];
    if (threadIdx.x < WF) lc[threadIdx.x] = 0;
    __syncthreads();
    int e0 = blockIdx.x * EPB;
    int pk[8], wl[8];
#pragma unroll
    for (int i = 0; i < 8; ++i) {
        int e = e0 + i * 256 + threadIdx.x;
        wl[i] = -1;
        if (e < N_EDGES) {
            int src = ei[e], dst = ei[N_EDGES + e];
            int w = dst >> LOGW;
            int lp = atomicAdd(&lc[w], 1);          // local slot within (block, window)
            pk[i] = ((dst - (w << LOGW)) << 16) | src;
            wl[i] = (w << 16) | lp;
        }
    }
    __syncthreads();
    if (threadIdx.x < WF)
        lb[threadIdx.x] = atomicAdd(&cursor[threadIdx.x], lc[threadIdx.x]);
    __syncthreads();
#pragma unroll
    for (int i = 0; i < 8; ++i) {
        if (wl[i] >= 0) {
            int w = wl[i] >> 16, lp = wl[i] & 0xffff;
            int pos = lb[w] + lp;
            if (pos < CAP) bucket[w * CAP + pos] = pk[i];
        }
    }
}

__global__ __launch_bounds__(256) void k_degb(const int* __restrict__ bucket,
                                              const int* __restrict__ cursor,
                                              float* __restrict__ degp) {
    __shared__ float hc[NWF];
    int w = blockIdx.x, c = blockIdx.y;
    float4* h4 = (float4*)hc;
    for (int i = threadIdx.x; i < NWF / 4; i += 256) h4[i] = make_float4(0, 0, 0, 0);
    __syncthreads();
    int cw = min(cursor[w], CAP);
    const int* bp = bucket + w * CAP;
    for (int e = c * 256 + threadIdx.x; e < cw; e += DC * 256)
        atomicAdd(&hc[((unsigned)bp[e]) >> 16], 1.0f);
    __syncthreads();
    int nb = w * NWF;
    for (int i = threadIdx.x; i < NWF; i += 256) {
        int n = nb + i;
        if (n < N_NODES) degp[c * N_NODES + n] = hc[i];
    }
}

__global__ __launch_bounds__(256) void k_scale_f(const float* __restrict__ x,
                                                 const float* __restrict__ degp,
                                                 float* __restrict__ dinv,
                                                 float* __restrict__ xs_pad) {
    int n = blockIdx.x * 256 + threadIdx.x;
    if (n >= N_NODES) return;
    float d = 1.0f;                       // self-loop
#pragma unroll
    for (int c = 0; c < DC; ++c) d += degp[c * N_NODES + n];
    float dv = rsqrtf(d);
    dinv[n] = dv;
    float4 a, b;
    a.x = x[n * 6 + 0] * dv; a.y = x[n * 6 + 1] * dv;
    a.z = x[n * 6 + 2] * dv; a.w = x[n * 6 + 3] * dv;
    b.x = x[n * 6 + 4] * dv; b.y = x[n * 6 + 5] * dv;
    b.z = 0.0f; b.w = 0.0f;
    ((float4*)(xs_pad + n * 8))[0] = a;
    ((float4*)(xs_pad + n * 8))[1] = b;
}

__global__ __launch_bounds__(256) void k_feat_b(const int* __restrict__ bucket,
                                                const int* __restrict__ cursor,
                                                const float* __restrict__ xs_pad,
                                                float* __restrict__ s_part) {
    __shared__ float h[NWF * 6];
    int w = blockIdx.x, c = blockIdx.y;
    float4* h4 = (float4*)h;
    for (int i = threadIdx.x; i < NWF * 6 / 4; i += 256) h4[i] = make_float4(0, 0, 0, 0);
    __syncthreads();
    int cw = min(cursor[w], CAP);
    const int* bp = bucket + w * CAP;
    for (int e = c * 256 + threadIdx.x; e < cw; e += CB * 256) {
        int p = bp[e];
        int u = ((unsigned)p) >> 16;
        int src = p & 0xffff;
        const float4* xp = (const float4*)(xs_pad + src * 8);
        float4 a = xp[0], b = xp[1];
        float* hp = &h[u * 6];
        atomicAdd(hp + 0, a.x); atomicAdd(hp + 1, a.y); atomicAdd(hp + 2, a.z);
        atomicAdd(hp + 3, a.w); atomicAdd(hp + 4, b.x); atomicAdd(hp + 5, b.y);
    }
    __syncthreads();
    int gb = w * NWF * 6;
    int lim = min(NWF * 6, N6 - gb);      // multiple of 4
    float4* sp4 = (float4*)(s_part + (size_t)c * N6 + gb);
    for (int i = threadIdx.x; i < lim / 4; i += 256) sp4[i] = h4[i];
}

// block: NBLK nodes; partial-reduce into LDS, W1+ReLU, per-graph LDS rows,
// flush interior graphs with plain stores, boundary graphs with atomics.
__global__ __launch_bounds__(256) void k_node_f(const float* __restrict__ s_part,
                                                const float* __restrict__ xs_pad,
                                                const float* __restrict__ dinv,
                                                const int* __restrict__ batch,
                                                const float* __restrict__ w1,
                                                const float* __restrict__ b1,
                                                float* __restrict__ gsum,
                                                float* __restrict__ cnt) {
    __shared__ float sb[NBLK * 6];
    __shared__ float dvb[NBLK];
    __shared__ int   btb[NBLK];
    __shared__ float gacc[MAXSPAN][HID];
    __shared__ float gcnt[MAXSPAN];
    __shared__ int   sbnd[2];

    int nb0 = blockIdx.x * NBLK;
    int nEnd = min(nb0 + NBLK, N_NODES);
    int nCnt = nEnd - nb0;
    int lim = nCnt * 6;                       // multiple of 4 (nCnt even)

    // phase A: partial reduce into sb (float4), plus loads and zeroing
    {
        float4* sb4 = (float4*)sb;
        int nv = lim >> 2;
        int g4base = (nb0 * 6) >> 2;          // nb0*6 divisible by 4
        for (int i = threadIdx.x; i < nv; i += 256) {
            float4 v = make_float4(0, 0, 0, 0);
#pragma unroll
            for (int c = 0; c < CB; ++c) {
                float4 p = ((const float4*)(s_part + (size_t)c * N6))[g4base + i];
                v.x += p.x; v.y += p.y; v.z += p.z; v.w += p.w;
            }
            sb4[i] = v;
        }
    }
    for (int i = threadIdx.x; i < nCnt; i += 256) {
        dvb[i] = dinv[nb0 + i];
        btb[i] = batch[nb0 + i];
    }
    if (threadIdx.x == 0) {
        sbnd[0] = (nb0 > 0) ? batch[nb0 - 1] : -1;
        sbnd[1] = (nEnd < N_NODES) ? batch[nEnd] : -1;
    }
    for (int i = threadIdx.x; i < MAXSPAN * HID; i += 256) ((float*)gacc)[i] = 0.0f;
    if (threadIdx.x < MAXSPAN) gcnt[threadIdx.x] = 0.0f;
    __syncthreads();

    // phase B: add self-loop term
    for (int i = threadIdx.x; i < lim; i += 256) {
        int n = nb0 + i / 6, k = i - (i / 6) * 6;
        sb[i] += xs_pad[n * 8 + k];
    }
    __syncthreads();

    // phase C: compute + accumulate
    int f = threadIdx.x & (HID - 1);
    int sub = threadIdx.x >> 7;
    float w1r[6];
#pragma unroll
    for (int k = 0; k < 6; ++k) w1r[k] = w1[k * HID + f];
    float b1f = b1[f];

    int bfirst = btb[0];
    int blast = btb[nCnt - 1];
    int span = blast - bfirst + 1;
    int bprev = sbnd[0], bnext = sbnd[1];
    int i0 = sub * (NBLK / 2);
    int i1 = min(i0 + (NBLK / 2), nCnt);

    if (span <= MAXSPAN) {
        float acc = 0.0f, rc = 0.0f;
        int curb = -1;
        for (int i = i0; i < i1; ++i) {
            const float* sp = &sb[i * 6];
            float t = 0.0f;
#pragma unroll
            for (int k = 0; k < 6; ++k) t = fmaf(sp[k], w1r[k], t);
            float a = fmaxf(fmaf(dvb[i], t, b1f), 0.0f);
            int b = btb[i];
            if (b != curb) {
                if (curb >= 0) {
                    atomicAdd(&gacc[curb - bfirst][f], acc);
                    if (f == 0) atomicAdd(&gcnt[curb - bfirst], rc);
                }
                acc = 0.0f; rc = 0.0f; curb = b;
            }
            acc += a; rc += 1.0f;
        }
        if (curb >= 0) {
            atomicAdd(&gacc[curb - bfirst][f], acc);
            if (f == 0) atomicAdd(&gcnt[curb - bfirst], rc);
        }
        __syncthreads();
        for (int idx = threadIdx.x; idx < span * HID; idx += 256) {
            int r = idx >> 7, ff = idx & (HID - 1);
            int gid = bfirst + r;
            float v = gacc[r][ff];
            if (gid == bprev || gid == bnext) atomicAdd(&gsum[gid * HID + ff], v);
            else gsum[gid * HID + ff] = v;
        }
        if (threadIdx.x < span) {
            int gid = bfirst + threadIdx.x;
            float v = gcnt[threadIdx.x];
            if (gid == bprev || gid == bnext) atomicAdd(&cnt[gid], v);
            else cnt[gid] = v;
        }
    } else {
        // safety fallback: direct global atomics per run
        float acc = 0.0f, rc = 0.0f;
        int curb = -1;
        for (int i = i0; i < i1; ++i) {
            const float* sp = &sb[i * 6];
            float t = 0.0f;
#pragma unroll
            for (int k = 0; k < 6; ++k) t = fmaf(sp[k], w1r[k], t);
            float a = fmaxf(fmaf(dvb[i], t, b1f), 0.0f);
            int b = btb[i];
            if (b != curb) {
                if (curb >= 0) {
                    atomicAdd(&gsum[curb * HID + f], acc);
                    if (f == 0) atomicAdd(&cnt[curb], rc);
                }
                acc = 0.0f; rc = 0.0f; curb = b;
            }
            acc += a; rc += 1.0f;
        }
        if (curb >= 0) {
            atomicAdd(&gsum[curb * HID + f], acc);
            if (f == 0) atomicAdd(&cnt[curb], rc);
        }
    }
}

__global__ __launch_bounds__(128) void k_head(const float* __restrict__ gsum,
                                              const float* __restrict__ cnt,
                                              const float* __restrict__ wl,
                                              const float* __restrict__ bl,
                                              const float* __restrict__ w2,
                                              const float* __restrict__ b2,
                                              float* __restrict__ out) {
    __shared__ float sg[HID];
    __shared__ float sg2[HID];
    int g = blockIdx.x;
    int t = threadIdx.x;

    float ic = 1.0f / fmaxf(cnt[g], 1.0f);
    sg[t] = gsum[g * HID + t] * ic;
    __syncthreads();

    float acc = bl[t];
    for (int k = 0; k < HID; ++k) acc = fmaf(sg[k], wl[k * HID + t], acc);
    sg2[t] = fmaxf(acc, 0.0f);
    __syncthreads();

    if (t < N_ACT) {
        float l = b2[t];
        for (int f = 0; f < HID; ++f) l = fmaf(sg2[f], w2[f * N_ACT + t], l);
        float m = l;
#pragma unroll
        for (int off = 32; off > 0; off >>= 1) m = fmaxf(m, __shfl_xor(m, off));
        float e = expf(l - m);
        float ssum = e;
#pragma unroll
        for (int off = 32; off > 0; off >>= 1) ssum += __shfl_xor(ssum, off);
        out[g * N_ACT + t] = l - m - logf(ssum);
    }
}

// ===================== fallback path (round-1, known-correct) =====================

__global__ void k_init(float* __restrict__ deg, float* __restrict__ gsum,
                       float* __restrict__ cnt) {
    int i = blockIdx.x * blockDim.x + threadIdx.x;
    if (i < N_NODES) deg[i] = 1.0f;
    if (i < N_GRAPH * HID) gsum[i] = 0.0f;
    if (i < N_GRAPH) cnt[i] = 0.0f;
}

__global__ void k_deg(const int* __restrict__ ei, float* __restrict__ deg) {
    int e = blockIdx.x * blockDim.x + threadIdx.x;
    if (e < N_EDGES) atomicAdd(&deg[ei[N_EDGES + e]], 1.0f);
}

__global__ void k_scale(const float* __restrict__ x, const int* __restrict__ batch,
                        const float* __restrict__ deg, float* __restrict__ dinv,
                        float* __restrict__ xs, float* __restrict__ s,
                        float* __restrict__ cnt) {
    int n = blockIdx.x * blockDim.x + threadIdx.x;
    if (n >= N_NODES) return;
    float dv = rsqrtf(deg[n]);
    dinv[n] = dv;
#pragma unroll
    for (int k = 0; k < 6; ++k) {
        float v = x[n * 6 + k] * dv;
        xs[n * 6 + k] = v;
        s[n * 6 + k] = v;
    }
    atomicAdd(&cnt[batch[n]], 1.0f);
}

__global__ void k_scatter(const int* __restrict__ ei, const float* __restrict__ xs,
                          float* __restrict__ s) {
    int e = blockIdx.x * blockDim.x + threadIdx.x;
    if (e >= N_EDGES) return;
    int src = ei[e];
    int dst = ei[N_EDGES + e];
#pragma unroll
    for (int k = 0; k < 6; ++k)
        atomicAdd(&s[dst * 6 + k], xs[src * 6 + k]);
}

__global__ __launch_bounds__(256) void k_node(const float* __restrict__ s,
                                              const float* __restrict__ dinv,
                                              const int* __restrict__ batch,
                                              const float* __restrict__ w1,
                                              const float* __restrict__ b1,
                                              float* __restrict__ gsum) {
    int f = threadIdx.x & (HID - 1);
    int sub = threadIdx.x >> 7;
    int base = blockIdx.x * 16 + sub * 8;
    float w1r[6];
#pragma unroll
    for (int k = 0; k < 6; ++k) w1r[k] = w1[k * HID + f];
    float b1f = b1[f];
    float acc = 0.0f;
    int curb = -1;
    for (int i = 0; i < 8; ++i) {
        int n = base + i;
        if (n >= N_NODES) break;
        float t = 0.0f;
#pragma unroll
        for (int k = 0; k < 6; ++k) t = fmaf(s[n * 6 + k], w1r[k], t);
        float a = fmaxf(fmaf(dinv[n], t, b1f), 0.0f);
        int b = batch[n];
        if (b != curb) {
            if (curb >= 0) atomicAdd(&gsum[curb * HID + f], acc);
            acc = 0.0f;
            curb = b;
        }
        acc += a;
    }
    if (curb >= 0) atomicAdd(&gsum[curb * HID + f], acc);
}

// ===================== launch =====================

extern "C" void kernel_launch(void* const* d_in, const int* in_sizes, int n_in,
                              void* d_out, int out_size, void* d_ws, size_t ws_size,
                              hipStream_t stream) {
    const float* x     = (const float*)d_in[0];
    const int*   ei    = (const int*)d_in[1];
    const int*   batch = (const int*)d_in[2];
    const float* w1    = (const float*)d_in[3];
    const float* b1    = (const float*)d_in[4];
    const float* wl    = (const float*)d_in[5];
    const float* bl    = (const float*)d_in[6];
    const float* w2    = (const float*)d_in[7];
    const float* b2    = (const float*)d_in[8];
    float* out = (float*)d_out;
    float* ws = (float*)d_ws;

    if (ws_size >= NEED_BYTES) {
        int*   bucket = (int*)(ws + F_BUCKET);
        int*   cursor = (int*)(ws + F_CURSOR);
        float* degp   = ws + F_DEGP;
        float* dinv   = ws + F_DINV;
        float* xs_pad = ws + F_XSPAD;
        float* s_part = ws + F_SPART;
        float* gsum   = ws + F_GSUM;
        float* cnt    = ws + F_CNT;

        k_init_f<<<(N_GRAPH * HID + 255) / 256, 256, 0, stream>>>(gsum, cnt, cursor);
        k_place<<<PB, 256, 0, stream>>>(ei, bucket, cursor);
        k_degb<<<dim3(WF, DC), 256, 0, stream>>>(bucket, cursor, degp);
        k_scale_f<<<(N_NODES + 255) / 256, 256, 0, stream>>>(x, degp, dinv, xs_pad);
        k_feat_b<<<dim3(WF, CB), 256, 0, stream>>>(bucket, cursor, xs_pad, s_part);
        k_node_f<<<(N_NODES + NBLK - 1) / NBLK, 256, 0, stream>>>(s_part, xs_pad, dinv, batch, w1, b1, gsum, cnt);
        k_head<<<N_GRAPH, 128, 0, stream>>>(gsum, cnt, wl, bl, w2, b2, out);
    } else {
        float* deg  = ws;
        float* dinv = deg + N_NODES;
        float* xs   = dinv + N_NODES;
        float* s    = xs + N6;
        float* gsum = s + N6;
        float* cnt  = gsum + N_GRAPH * HID;

        k_init<<<(N_GRAPH * HID + 255) / 256, 256, 0, stream>>>(deg, gsum, cnt);
        k_deg<<<(N_EDGES + 255) / 256, 256, 0, stream>>>(ei, deg);
        k_scale<<<(N_NODES + 255) / 256, 256, 0, stream>>>(x, batch, deg, dinv, xs, s, cnt);
        k_scatter<<<(N_EDGES + 255) / 256, 256, 0, stream>>>(ei, xs, s);
        k_node<<<(N_NODES + 15) / 16, 256, 0, stream>>>(s, dinv, batch, w1, b1, gsum);
        k_head<<<N_GRAPH, 128, 0, stream>>>(gsum, cnt, wl, bl, w2, b2, out);
    }
}